// Round 5
// baseline (444.838 us; speedup 1.0000x reference)
//
#include <hip/hip_runtime.h>
#include <hip/hip_bf16.h>

// NeuralTuringMachine  B=2048, IN=256, C=256, M=1024, D=32, OUT=256
// Inputs fp32. OUTPUT BUFFER IS FP32 (reference output dtype float32).
// Round-4 diagnostic confirmed: n_in=16, all in_sizes match dict order,
// ws_size >= 11MB. The 0.748 = sqrt(2)*0.531 signature was bf16-packed
// output being read back as fp32. Fix: store fp32 outputs.
// h=c=0 => read head batch-independent; W_rattn/W_hh dead; f-gate dead.

#define BB   2048
#define CCC  256
#define MMM  1024
#define DDD  32
#define OUTN 256

typedef __attribute__((ext_vector_type(4))) float f32x4;
typedef __attribute__((ext_vector_type(2))) float f32x2;

__device__ __forceinline__ float sigmoidf_(float x){ return 1.0f/(1.0f+__expf(-x)); }

// ---------------- kernel 1: prep (1 block) ----------------
// w_r = softmax(b_rattn); read_data = w_r @ memory;
// biasv[j]   = b_ih[j]+b_hh[j]+dot(W_ih[j,256:288], read_data)
// out_bias[o]= b_out[o]+dot(W_out[o,256:288], read_data)
__global__ __launch_bounds__(256) void k_prep(
    const float* __restrict__ b_rattn,
    const float* __restrict__ memory,
    const float* __restrict__ W_ih,
    const float* __restrict__ b_ih,
    const float* __restrict__ b_hh,
    const float* __restrict__ W_out,
    const float* __restrict__ b_out,
    float* __restrict__ biasv,     // [1024]
    float* __restrict__ out_bias)  // [256]
{
  __shared__ float wr[MMM];
  __shared__ float red[256];
  __shared__ float rds[DDD];
  int t = threadIdx.x;
  float v[4], mx = -1e30f;
  #pragma unroll
  for (int j=0;j<4;++j){ v[j] = b_rattn[t + j*256]; mx = fmaxf(mx, v[j]); }
  red[t]=mx; __syncthreads();
  for (int s=128;s>0;s>>=1){ if(t<s) red[t]=fmaxf(red[t],red[t+s]); __syncthreads(); }
  float M = red[0]; __syncthreads();
  float ls=0.f;
  #pragma unroll
  for (int j=0;j<4;++j){ float e=__expf(v[j]-M); wr[t+j*256]=e; ls+=e; }
  red[t]=ls; __syncthreads();
  for (int s=128;s>0;s>>=1){ if(t<s) red[t]+=red[t+s]; __syncthreads(); }
  float invS = 1.0f/red[0];
  __syncthreads();
  int d = t & 31, chunk = t >> 5;
  float p = 0.f;
  for (int m=chunk*128; m<chunk*128+128; ++m) p += wr[m]*memory[m*DDD+d];
  red[t]=p; __syncthreads();
  if (chunk==0){
    float s2=0.f;
    #pragma unroll
    for (int c2=0;c2<8;++c2) s2 += red[c2*32 + d];
    rds[d] = s2*invS;
  }
  __syncthreads();
  #pragma unroll
  for (int jj=0;jj<4;++jj){
    int j = t + jj*256;
    float s2 = b_ih[j] + b_hh[j];
    const float* wrow = W_ih + j*288 + 256;
    #pragma unroll
    for (int d2=0; d2<DDD; ++d2) s2 += wrow[d2]*rds[d2];
    biasv[j]=s2;
  }
  {
    float s2 = b_out[t];
    const float* wrow = W_out + t*288 + 256;
    #pragma unroll
    for (int d2=0; d2<DDD; ++d2) s2 += wrow[d2]*rds[d2];
    out_bias[t]=s2;
  }
}

// ---------------- kernel 2: gates GEMM (VALU fp32) + LSTM activation ----------------
// h = sigmoid(o) * tanh(sigmoid(i) * tanh(g))   (f-gate dead, c=0)
__global__ __launch_bounds__(256) void k_gates(
    const float* __restrict__ x,
    const float* __restrict__ W_ih,
    const float* __restrict__ biasv,
    float* __restrict__ h_newf)
{
  __shared__ float As[32][32];       // [k][m]
  __shared__ float Bs[3][32][64];    // [gate][k][n]
  const int grow[3] = {0, 512, 768}; // i, g, o row blocks of W_ih

  int t  = threadIdx.x;
  int mt = blockIdx.x >> 2;
  int nt = blockIdx.x & 3;
  int m0 = mt*32, n0 = nt*64;
  int tm = t >> 4;
  int tn = t & 15;

  float acc[3][2][4];
  #pragma unroll
  for (int g=0; g<3; ++g)
    #pragma unroll
    for (int im=0; im<2; ++im)
      #pragma unroll
      for (int in=0; in<4; ++in) acc[g][im][in]=0.f;

  int am  = t >> 3, akq = t & 7;
  int bn  = t >> 2, bkq = t & 3;

  for (int k0=0; k0<CCC; k0+=32){
    f32x4 av = *(const f32x4*)(x + (m0+am)*CCC + k0 + akq*4);
    #pragma unroll
    for (int i=0;i<4;++i) As[akq*4+i][am] = av[i];
    #pragma unroll
    for (int g=0; g<3; ++g){
      const float* wrow = W_ih + (grow[g] + n0 + bn)*288 + k0 + bkq*8;
      f32x4 b0 = *(const f32x4*)wrow;
      f32x4 b1 = *(const f32x4*)(wrow+4);
      #pragma unroll
      for (int i=0;i<4;++i){ Bs[g][bkq*8+i][bn]=b0[i]; Bs[g][bkq*8+4+i][bn]=b1[i]; }
    }
    __syncthreads();
    #pragma unroll 8
    for (int k=0;k<32;++k){
      f32x2 a2 = *(const f32x2*)&As[k][tm*2];
      f32x4 b0 = *(const f32x4*)&Bs[0][k][tn*4];
      f32x4 b1 = *(const f32x4*)&Bs[1][k][tn*4];
      f32x4 b2 = *(const f32x4*)&Bs[2][k][tn*4];
      #pragma unroll
      for (int im=0; im<2; ++im){
        #pragma unroll
        for (int in=0; in<4; ++in){
          acc[0][im][in] = __fmaf_rn(a2[im], b0[in], acc[0][im][in]);
          acc[1][im][in] = __fmaf_rn(a2[im], b1[in], acc[1][im][in]);
          acc[2][im][in] = __fmaf_rn(a2[im], b2[in], acc[2][im][in]);
        }
      }
    }
    __syncthreads();
  }

  #pragma unroll
  for (int im=0; im<2; ++im){
    int m = m0 + tm*2 + im;
    #pragma unroll
    for (int in=0; in<4; ++in){
      int c = n0 + tn*4 + in;
      float ig = sigmoidf_(acc[0][im][in] + biasv[c]);
      float gg = tanhf   (acc[1][im][in] + biasv[512+c]);
      float og = sigmoidf_(acc[2][im][in] + biasv[768+c]);
      h_newf[m*CCC + c] = og * tanhf(ig*gg);
    }
  }
}

// ---------------- kernel 3: fused second GEMM (VALU fp32) ----------------
// h @ [W_wattn | W_er | W_ad | W_out[:, :256]].T   N = 1024+32+32+256 = 1344
__global__ __launch_bounds__(256) void k_big(
    const float* __restrict__ h_newf,
    const float* __restrict__ W_wattn,
    const float* __restrict__ b_wattn,
    const float* __restrict__ W_er,
    const float* __restrict__ b_er,
    const float* __restrict__ W_ad,
    const float* __restrict__ b_ad,
    const float* __restrict__ W_out,
    const float* __restrict__ out_bias,
    float* __restrict__ wlogits,   // [2048,1024]
    float* __restrict__ erasev,    // [2048,32]
    float* __restrict__ addv,      // [2048,32]
    float* __restrict__ outp)      // [2048,256] -> d_out (fp32)
{
  __shared__ float As[32][32];
  __shared__ float Bs[32][64];

  int t  = threadIdx.x;
  int mt = blockIdx.x / 21;
  int nt = blockIdx.x % 21;
  int m0 = mt*32, n0 = nt*64;
  int tm = t >> 4, tn = t & 15;

  float acc[2][4];
  #pragma unroll
  for (int im=0; im<2; ++im)
    #pragma unroll
    for (int in=0; in<4; ++in) acc[im][in]=0.f;

  int am = t >> 3, akq = t & 7;
  int bn = t >> 2, bkq = t & 3;
  int nrow = n0 + bn;
  const float* brow;
  if      (nrow < 1024) brow = W_wattn + nrow*256;
  else if (nrow < 1056) brow = W_er    + (nrow-1024)*256;
  else if (nrow < 1088) brow = W_ad    + (nrow-1056)*256;
  else                  brow = W_out   + (nrow-1088)*288;

  for (int k0=0; k0<CCC; k0+=32){
    f32x4 av = *(const f32x4*)(h_newf + (m0+am)*CCC + k0 + akq*4);
    #pragma unroll
    for (int i=0;i<4;++i) As[akq*4+i][am] = av[i];
    f32x4 b0 = *(const f32x4*)(brow + k0 + bkq*8);
    f32x4 b1 = *(const f32x4*)(brow + k0 + bkq*8 + 4);
    #pragma unroll
    for (int i=0;i<4;++i){ Bs[bkq*8+i][bn]=b0[i]; Bs[bkq*8+4+i][bn]=b1[i]; }
    __syncthreads();
    #pragma unroll 8
    for (int k=0;k<32;++k){
      f32x2 a2 = *(const f32x2*)&As[k][tm*2];
      f32x4 bv = *(const f32x4*)&Bs[k][tn*4];
      #pragma unroll
      for (int im=0; im<2; ++im)
        #pragma unroll
        for (int in=0; in<4; ++in)
          acc[im][in] = __fmaf_rn(a2[im], bv[in], acc[im][in]);
    }
    __syncthreads();
  }

  #pragma unroll
  for (int im=0; im<2; ++im){
    int m = m0 + tm*2 + im;
    #pragma unroll
    for (int in=0; in<4; ++in){
      int c = n0 + tn*4 + in;
      float v = acc[im][in];
      if (c < 1024){
        wlogits[(size_t)m*MMM + c] = v + b_wattn[c];
      } else if (c < 1056){
        int dc = c - 1024;
        erasev[m*DDD + dc] = sigmoidf_(v + b_er[dc]);
      } else if (c < 1088){
        int dc = c - 1056;
        addv[m*DDD + dc] = tanhf(v + b_ad[dc]);
      } else {
        int oc = c - 1088;
        outp[m*OUTN + oc] = v + out_bias[oc];   // fp32 store
      }
    }
  }
}

// ---------------- kernel 4: row softmax + rank-1 erase/add write (fp32 out) ----------------
__global__ __launch_bounds__(256) void k_write(
    const float* __restrict__ wlogits,
    const float* __restrict__ erasev,
    const float* __restrict__ addv,
    const float* __restrict__ memory,
    float* __restrict__ wd)        // [2048,1024,32] fp32
{
  __shared__ float sw[MMM];
  __shared__ float red[256];
  int b = blockIdx.x;
  int t = threadIdx.x;
  const float* lrow = wlogits + (size_t)b*MMM;
  float v[4], mx = -1e30f;
  #pragma unroll
  for (int j=0;j<4;++j){ v[j]=lrow[t+j*256]; mx=fmaxf(mx,v[j]); }
  red[t]=mx; __syncthreads();
  for (int s=128;s>0;s>>=1){ if(t<s) red[t]=fmaxf(red[t],red[t+s]); __syncthreads(); }
  float M = red[0]; __syncthreads();
  float ls=0.f;
  #pragma unroll
  for (int j=0;j<4;++j){ float e=__expf(v[j]-M); sw[t+j*256]=e; ls+=e; }
  red[t]=ls; __syncthreads();
  for (int s=128;s>0;s>>=1){ if(t<s) red[t]+=red[t+s]; __syncthreads(); }
  float invS = 1.0f/red[0];

  int d0   = (t&3)*8;     // 8 floats = 32 B per thread
  int mSub = t>>2;
  float e8[8], a8[8];
  #pragma unroll
  for (int j=0;j<8;++j){ e8[j]=erasev[b*DDD + d0 + j]; a8[j]=addv[b*DDD + d0 + j]; }

  float* orow = wd + (size_t)b*MMM*DDD;
  #pragma unroll 4
  for (int pass=0; pass<16; ++pass){
    int m = pass*64 + mSub;
    float w = sw[m]*invS;
    f32x4 m0_ = *(const f32x4*)(memory + m*DDD + d0);
    f32x4 m1_ = *(const f32x4*)(memory + m*DDD + d0 + 4);
    f32x4 o0, o1;
    #pragma unroll
    for (int j=0;j<4;++j){
      o0[j] = __fmaf_rn(m0_[j], 1.0f - w*e8[j],   w*a8[j]);
      o1[j] = __fmaf_rn(m1_[j], 1.0f - w*e8[4+j], w*a8[4+j]);
    }
    *(f32x4*)(orow + m*DDD + d0)     = o0;
    *(f32x4*)(orow + m*DDD + d0 + 4) = o1;
  }
}

extern "C" void kernel_launch(void* const* d_in, const int* in_sizes, int n_in,
                              void* d_out, int out_size, void* d_ws, size_t ws_size,
                              hipStream_t stream) {
  const float* x       = (const float*)d_in[0];
  const float* memory  = (const float*)d_in[1];
  // d_in[2] = W_rattn : dead (h=0)
  const float* b_rattn = (const float*)d_in[3];
  const float* W_ih    = (const float*)d_in[4];
  // d_in[5] = W_hh : dead (h=0)
  const float* b_ih    = (const float*)d_in[6];
  const float* b_hh    = (const float*)d_in[7];
  const float* W_wattn = (const float*)d_in[8];
  const float* b_wattn = (const float*)d_in[9];
  const float* W_er    = (const float*)d_in[10];
  const float* b_er    = (const float*)d_in[11];
  const float* W_ad    = (const float*)d_in[12];
  const float* b_ad    = (const float*)d_in[13];
  const float* W_out   = (const float*)d_in[14];
  const float* b_out   = (const float*)d_in[15];

  float* outp = (float*)d_out;                  // [2048,256] fp32
  float* wd   = outp + (size_t)BB*OUTN;         // [2048,1024,32] fp32

  char* ws = (char*)d_ws;
  float* biasv    = (float*)ws;                                   // 4 KB
  float* out_bias = (float*)(ws + 4096);                          // -> 5120
  float* h_newf   = (float*)(ws + 5120);                          // 2 MB
  float* wlogits  = (float*)(ws + 5120 + (size_t)BB*CCC*4);       // 8 MB
  float* erasev   = wlogits + (size_t)BB*MMM;                     // 256 KB
  float* addv     = erasev  + (size_t)BB*DDD;                     // 256 KB

  k_prep <<<1,    256, 0, stream>>>(b_rattn, memory, W_ih, b_ih, b_hh, W_out, b_out,
                                    biasv, out_bias);
  k_gates<<<256,  256, 0, stream>>>(x, W_ih, biasv, h_newf);
  k_big  <<<1344, 256, 0, stream>>>(h_newf, W_wattn, b_wattn, W_er, b_er, W_ad, b_ad,
                                    W_out, out_bias, wlogits, erasev, addv, outp);
  k_write<<<2048, 256, 0, stream>>>(wlogits, erasev, addv, memory, wd);
}